// Round 9
// baseline (60.432 us; speedup 1.0000x reference)
//
#include <hip/hip_runtime.h>

// SE(2) depthwise group conv via bf16 MFMA (fp32 accum).
// Per (b,c): out[8t][16384 pix] = W[8 x 200] @ im2col(x)[200 x 16384]
//   K = 28 taps x 8 orientations (o innermost), taps 25-27 zero weights.
// mfma_f32_16x16x32_bf16, A = x-frag (rows = 16 pixels), B = w-frag (cols = t):
//   A lane l: row = l&15 (pixel), k = 8*(l>>4)+j
//   B lane l: col = l&15 (t; 8 real + 8 zero), k = 8*(l>>4)+j
//   D lane l: col = l&15 (t), row = (l>>4)*4+reg (pixel) -> float4 store.
// Block = 16-row x 32-col tile of one (b,c). LDS x-buf [20 r][36 c][8 o] bf16
// = 11.5 KB (+3.5 KB weights) -> 8 blocks/CU (wave-capped), 2x R8 occupancy.
// Staging: 2 full rounds + 1 partial (720 chunks), loads batched per round.
// Grid 8192, XCD-chunked swizzle: the 32 blocks of one (b,c) share an XCD.

typedef short bf16x8 __attribute__((ext_vector_type(8)));
typedef float f32x4 __attribute__((ext_vector_type(4)));

__device__ inline unsigned short f2bf(float f) {   // RNE f32->bf16
    unsigned int u = __float_as_uint(f);
    u += 0x7fffu + ((u >> 16) & 1u);
    return (unsigned short)(u >> 16);
}
__device__ inline unsigned pk2(float a, float b) {
    return (unsigned)f2bf(a) | ((unsigned)f2bf(b) << 16);
}

// cos/sin of 2*pi*t/8, f32. NN-rounding margins >=0.035 -> table-vs-libm safe.
__device__ __constant__ float CA8[8] = {1.0f, 0.70710678f, 0.0f, -0.70710678f,
                                        -1.0f, -0.70710678f, 0.0f, 0.70710678f};
__device__ __constant__ float SA8[8] = {0.0f, 0.70710678f, 1.0f, 0.70710678f,
                                        0.0f, -0.70710678f, -1.0f, -0.70710678f};

__global__ __launch_bounds__(256)
void se2_mfma(const float* __restrict__ x, const float* __restrict__ kern,
              float* __restrict__ out) {
    __shared__ __align__(16) unsigned short ldsx[20 * 36 * 8];  // 11520 B
    __shared__ __align__(16) unsigned short ldsw[8 * 28 * 8];   //  3584 B

    // XCD-chunked bijective swizzle: 8192 blocks, 8 XCDs, 1024 per XCD.
    const int bid = (blockIdx.x & 7) * 1024 + (blockIdx.x >> 3);
    const int tx = bid & 3;            // 4 x-tiles of 32 cols
    const int ys = (bid >> 2) & 7;     // 8 row-strips of 16
    const int bc = bid >> 5;           // b*32 + c
    const int c  = bc & 31;
    const int X0 = tx * 32, Y0 = ys * 16;
    const int tid = threadIdx.x;

    // ---- rotated weights -> ldsw[t][tap][o] bf16 (tap>=25 => 0) ----
    for (int e = tid; e < 1792; e += 256) {
        int t   = e / 224;
        int rem = e - t * 224;
        int tap = rem >> 3;
        int o   = rem & 7;
        float w = 0.0f;
        if (tap < 25) {
            int dy = tap / 5, dx = tap - 5 * (tap / 5);
            float ca = CA8[t], sa = SA8[t];
            float xx = (float)dx - 2.0f, yy = (float)dy - 2.0f;
            int iy = (int)rintf(sa * xx + ca * yy + 2.0f);  // RNE == jnp.round
            int ix = (int)rintf(ca * xx - sa * yy + 2.0f);
            if (iy >= 0 && iy < 5 && ix >= 0 && ix < 5) {
                int tp = (o - t) & 7;
                w = kern[(c * 8 + tp) * 25 + iy * 5 + ix];
            }
        }
        ldsw[e] = f2bf(w);
    }
    __syncthreads();   // ldsw producer -> wfrag consumer

    const float* xbase = x + (size_t)bc * 131072;

    auto loadch = [&](int e, float (&v)[8]) {
        int r = e / 36, col = e - r * 36;
        int gy = Y0 - 2 + r, gx = X0 - 2 + col;
        if (gy >= 0 && gy < 128 && gx >= 0 && gx < 128) {
            const float* src = xbase + gy * 128 + gx;
#pragma unroll
            for (int o = 0; o < 8; ++o) v[o] = src[o * 16384];
        } else {
#pragma unroll
            for (int o = 0; o < 8; ++o) v[o] = 0.0f;
        }
    };
    auto packch = [&](int e, const float (&v)[8]) {
        *reinterpret_cast<uint4*>(&ldsx[e * 8]) =
            make_uint4(pk2(v[0], v[1]), pk2(v[2], v[3]),
                       pk2(v[4], v[5]), pk2(v[6], v[7]));
    };

    const int lane  = tid & 63;
    const int wv    = tid >> 6;        // wave: rows y = wv*4 .. wv*4+3
    const int g     = lane >> 4;       // k-group
    const int col16 = lane & 15;
    const bool has2 = (tid < 720 - 512);   // 208 threads own a 3rd chunk

    float sA[8], sB[8];

    // round 1 loads issued first: their latency hides the wfrag ds_reads
    loadch(tid, sA);
    loadch(tid + 256, sB);

    bf16x8 wfrag[7];
    int    tapoff[7];
    const bf16x8 zfrag = {0, 0, 0, 0, 0, 0, 0, 0};
#pragma unroll
    for (int cc = 0; cc < 7; ++cc) {
        int tap  = cc * 4 + g;
        int tapc = tap < 25 ? tap : 24;
        int dy = tapc / 5, dx = tapc - 5 * (tapc / 5);
        tapoff[cc] = (dy * 36 + dx) * 8;          // in shorts
        wfrag[cc] = (col16 < 8)
            ? *reinterpret_cast<const bf16x8*>(&ldsw[(col16 * 28 + tap) * 8])
            : zfrag;
    }

    packch(tid, sA);
    packch(tid + 256, sB);
    if (has2) { loadch(tid + 512, sA); packch(tid + 512, sA); }
    __syncthreads();

    float* outl = out + (size_t)bc * 131072 + (size_t)col16 * 16384 +
                  (size_t)Y0 * 128 + X0 + g * 4;

    // ---- compute: 4 rows per wave, 2 xh per row, unroll 2 -> 4 chains ----
#pragma unroll 2
    for (int cp = 0; cp < 4; ++cp) {
        int y = wv * 4 + cp;
        int baseS = (y * 36 + col16) * 8;
        f32x4 acc0 = {0.f, 0.f, 0.f, 0.f};
        f32x4 acc1 = {0.f, 0.f, 0.f, 0.f};
#pragma unroll
        for (int cc = 0; cc < 7; ++cc) {
            bf16x8 xf0 = *reinterpret_cast<const bf16x8*>(&ldsx[baseS + tapoff[cc]]);
            bf16x8 xf1 = *reinterpret_cast<const bf16x8*>(&ldsx[baseS + 128 + tapoff[cc]]);
            acc0 = __builtin_amdgcn_mfma_f32_16x16x32_bf16(xf0, wfrag[cc], acc0, 0, 0, 0);
            acc1 = __builtin_amdgcn_mfma_f32_16x16x32_bf16(xf1, wfrag[cc], acc1, 0, 0, 0);
        }
        if (col16 < 8) {
            float* po = outl + (size_t)y * 128;
            *reinterpret_cast<float4*>(po)      = make_float4(acc0[0], acc0[1], acc0[2], acc0[3]);
            *reinterpret_cast<float4*>(po + 16) = make_float4(acc1[0], acc1[1], acc1[2], acc1[3]);
        }
    }
}

extern "C" void kernel_launch(void* const* d_in, const int* in_sizes, int n_in,
                              void* d_out, int out_size, void* d_ws, size_t ws_size,
                              hipStream_t stream) {
    const float* x    = (const float*)d_in[0];
    const float* kern = (const float*)d_in[1];
    float* out = (float*)d_out;
    dim3 grid(8192), block(256);   // 8b * 32c * 8ys * 4tx (swizzled in-kernel)
    se2_mfma<<<grid, block, 0, stream>>>(x, kern, out);
}

// Round 10
// 59.703 us; speedup vs baseline: 1.0122x; 1.0122x over previous
//
#include <hip/hip_runtime.h>

// SE(2) depthwise group conv via bf16 MFMA (fp32 accum).
// Per (b,c): out[8t][16384 pix] = W[8 x 200] @ im2col(x)[200 x 16384]
//   K = 28 taps x 8 orientations (o innermost), taps 25-27 zero weights.
// mfma_f32_16x16x32_bf16, A = x-frag (rows = 16 pixels), B = w-frag (cols = t):
//   D lane l: col = l&15 (t, 8 real), row = (l>>4)*4+reg (pixel) -> float4 store.
// R10: rotated-weight table precomputed ONCE by build_w into d_ws
// (wtab[c][t][tap][o] bf16, 114 KB, L2-resident); main kernel loads wfrags
// as 7 global dwordx4 per thread. No per-block weight build, no ldsw LDS.
// Block = 16-row x 32-col tile; LDS = [20 r][36 c][8 o] bf16 = 11.5 KB
// -> 8 blocks/CU (wave-capped). Grid 8192, XCD-chunked swizzle.

typedef short bf16x8 __attribute__((ext_vector_type(8)));
typedef float f32x4 __attribute__((ext_vector_type(4)));

__device__ inline unsigned short f2bf(float f) {   // RNE f32->bf16
    unsigned int u = __float_as_uint(f);
    u += 0x7fffu + ((u >> 16) & 1u);
    return (unsigned short)(u >> 16);
}
__device__ inline unsigned pk2(float a, float b) {
    return (unsigned)f2bf(a) | ((unsigned)f2bf(b) << 16);
}

// cos/sin of 2*pi*t/8, f32. NN-rounding margins >=0.035 -> table-vs-libm safe.
__device__ __constant__ float CA8[8] = {1.0f, 0.70710678f, 0.0f, -0.70710678f,
                                        -1.0f, -0.70710678f, 0.0f, 0.70710678f};
__device__ __constant__ float SA8[8] = {0.0f, 0.70710678f, 1.0f, 0.70710678f,
                                        0.0f, -0.70710678f, -1.0f, -0.70710678f};

// ---- weight-table build: wtab[((c*8+t)*28+tap)*8+o], 57344 bf16 ----
__global__ __launch_bounds__(256)
void build_w(const float* __restrict__ kern, unsigned short* __restrict__ wtab) {
    int e = blockIdx.x * 256 + threadIdx.x;
    if (e >= 57344) return;
    int o   = e & 7;
    int r1  = e >> 3;
    int tap = r1 % 28;
    int ct  = r1 / 28;
    int t   = ct & 7, c = ct >> 3;
    float w = 0.0f;
    if (tap < 25) {
        int dy = tap / 5, dx = tap - 5 * (tap / 5);
        float ca = CA8[t], sa = SA8[t];
        float xx = (float)dx - 2.0f, yy = (float)dy - 2.0f;
        int iy = (int)rintf(sa * xx + ca * yy + 2.0f);  // RNE == jnp.round
        int ix = (int)rintf(ca * xx - sa * yy + 2.0f);
        if (iy >= 0 && iy < 5 && ix >= 0 && ix < 5) {
            int tp = (o - t) & 7;
            w = kern[(c * 8 + tp) * 25 + iy * 5 + ix];
        }
    }
    wtab[e] = f2bf(w);
}

template <bool TAB>
__global__ __launch_bounds__(256)
void se2_mfma(const float* __restrict__ x, const float* __restrict__ kern,
              const unsigned short* __restrict__ wtab, float* __restrict__ out) {
    __shared__ __align__(16) unsigned short ldsx[20 * 36 * 8];  // 11520 B

    // XCD-chunked bijective swizzle: 8192 blocks, 8 XCDs, 1024 per XCD.
    const int bid = (blockIdx.x & 7) * 1024 + (blockIdx.x >> 3);
    const int tx = bid & 3;            // 4 x-tiles of 32 cols
    const int ys = (bid >> 2) & 7;     // 8 row-strips of 16
    const int bc = bid >> 5;           // b*32 + c
    const int c  = bc & 31;
    const int X0 = tx * 32, Y0 = ys * 16;
    const int tid = threadIdx.x;

    const int lane  = tid & 63;
    const int wv    = tid >> 6;        // wave: rows y = wv*4 .. wv*4+3
    const int g     = lane >> 4;       // k-group
    const int col16 = lane & 15;
    const bool has2 = (tid < 720 - 512);

    const float* xbase = x + (size_t)bc * 131072;

    auto loadch = [&](int e, float (&v)[8]) {
        int r = e / 36, col = e - r * 36;
        int gy = Y0 - 2 + r, gx = X0 - 2 + col;
        if (gy >= 0 && gy < 128 && gx >= 0 && gx < 128) {
            const float* src = xbase + gy * 128 + gx;
#pragma unroll
            for (int o = 0; o < 8; ++o) v[o] = src[o * 16384];
        } else {
#pragma unroll
            for (int o = 0; o < 8; ++o) v[o] = 0.0f;
        }
    };
    auto packch = [&](int e, const float (&v)[8]) {
        *reinterpret_cast<uint4*>(&ldsx[e * 8]) =
            make_uint4(pk2(v[0], v[1]), pk2(v[2], v[3]),
                       pk2(v[4], v[5]), pk2(v[6], v[7]));
    };

    float sA[8], sB[8];
    loadch(tid, sA);          // staging loads issued first (critical path)
    loadch(tid + 256, sB);

    bf16x8 wfrag[7];
    int    tapoff[7];
    const bf16x8 zfrag = {0, 0, 0, 0, 0, 0, 0, 0};

    if constexpr (TAB) {
        // per-lane weight frags straight from the L2-resident table
#pragma unroll
        for (int cc = 0; cc < 7; ++cc) {
            int tap  = cc * 4 + g;
            int tapc = tap < 25 ? tap : 24;
            int dy = tapc / 5, dx = tapc - 5 * (tapc / 5);
            tapoff[cc] = (dy * 36 + dx) * 8;      // in shorts
            wfrag[cc] = (col16 < 8)
                ? *reinterpret_cast<const bf16x8*>(&wtab[((c * 8 + col16) * 28 + tap) * 8])
                : zfrag;
        }
    } else {
        // fallback: build weights in LDS (R9 path), only if ws too small
        __shared__ __align__(16) unsigned short ldsw[8 * 28 * 8];
        for (int e = tid; e < 1792; e += 256) {
            int t   = e / 224;
            int rem = e - t * 224;
            int tap = rem >> 3;
            int o   = rem & 7;
            float w = 0.0f;
            if (tap < 25) {
                int dy = tap / 5, dx = tap - 5 * (tap / 5);
                float ca = CA8[t], sa = SA8[t];
                float xx = (float)dx - 2.0f, yy = (float)dy - 2.0f;
                int iy = (int)rintf(sa * xx + ca * yy + 2.0f);
                int ix = (int)rintf(ca * xx - sa * yy + 2.0f);
                if (iy >= 0 && iy < 5 && ix >= 0 && ix < 5) {
                    int tp = (o - t) & 7;
                    w = kern[(c * 8 + tp) * 25 + iy * 5 + ix];
                }
            }
            ldsw[e] = f2bf(w);
        }
        __syncthreads();
#pragma unroll
        for (int cc = 0; cc < 7; ++cc) {
            int tap  = cc * 4 + g;
            int tapc = tap < 25 ? tap : 24;
            int dy = tapc / 5, dx = tapc - 5 * (tapc / 5);
            tapoff[cc] = (dy * 36 + dx) * 8;
            wfrag[cc] = (col16 < 8)
                ? *reinterpret_cast<const bf16x8*>(&ldsw[(col16 * 28 + tap) * 8])
                : zfrag;
        }
    }

    packch(tid, sA);
    packch(tid + 256, sB);
    if (has2) { loadch(tid + 512, sA); packch(tid + 512, sA); }
    __syncthreads();

    float* outl = out + (size_t)bc * 131072 + (size_t)col16 * 16384 +
                  (size_t)Y0 * 128 + X0 + g * 4;

    // ---- compute: 4 rows per wave, 2 xh per row, unroll 2 -> 4 chains ----
#pragma unroll 2
    for (int cp = 0; cp < 4; ++cp) {
        int y = wv * 4 + cp;
        int baseS = (y * 36 + col16) * 8;
        f32x4 acc0 = {0.f, 0.f, 0.f, 0.f};
        f32x4 acc1 = {0.f, 0.f, 0.f, 0.f};
#pragma unroll
        for (int cc = 0; cc < 7; ++cc) {
            bf16x8 xf0 = *reinterpret_cast<const bf16x8*>(&ldsx[baseS + tapoff[cc]]);
            bf16x8 xf1 = *reinterpret_cast<const bf16x8*>(&ldsx[baseS + 128 + tapoff[cc]]);
            acc0 = __builtin_amdgcn_mfma_f32_16x16x32_bf16(xf0, wfrag[cc], acc0, 0, 0, 0);
            acc1 = __builtin_amdgcn_mfma_f32_16x16x32_bf16(xf1, wfrag[cc], acc1, 0, 0, 0);
        }
        if (col16 < 8) {
            float* po = outl + (size_t)y * 128;
            *reinterpret_cast<float4*>(po)      = make_float4(acc0[0], acc0[1], acc0[2], acc0[3]);
            *reinterpret_cast<float4*>(po + 16) = make_float4(acc1[0], acc1[1], acc1[2], acc1[3]);
        }
    }
}

extern "C" void kernel_launch(void* const* d_in, const int* in_sizes, int n_in,
                              void* d_out, int out_size, void* d_ws, size_t ws_size,
                              hipStream_t stream) {
    const float* x    = (const float*)d_in[0];
    const float* kern = (const float*)d_in[1];
    float* out = (float*)d_out;
    dim3 block(256);
    if (ws_size >= 57344 * sizeof(unsigned short)) {
        unsigned short* wtab = (unsigned short*)d_ws;
        build_w<<<dim3(224), block, 0, stream>>>(kern, wtab);
        se2_mfma<true><<<dim3(8192), block, 0, stream>>>(x, kern, wtab, out);
    } else {
        se2_mfma<false><<<dim3(8192), block, 0, stream>>>(x, kern, nullptr, out);
    }
}